// Round 12
// baseline (179.229 us; speedup 1.0000x reference)
//
#include <hip/hip_runtime.h>
#include <hip/hip_bf16.h>
#include <math.h>

typedef __bf16 bf16;
typedef bf16  bf16x8 __attribute__((ext_vector_type(8)));
typedef bf16  bf16x4 __attribute__((ext_vector_type(4)));
typedef float f32x4  __attribute__((ext_vector_type(4)));
typedef float f32x16 __attribute__((ext_vector_type(16)));
typedef unsigned int u32x2 __attribute__((ext_vector_type(2)));
typedef unsigned int u32x4 __attribute__((ext_vector_type(4)));

#define B_   4
#define N_   2048
#define CH_  512
#define H_   8
#define D_   64
#define HID_ 512

__device__ __forceinline__ f32x4 mfma16(bf16x8 a, bf16x8 b, f32x4 c) {
    return __builtin_amdgcn_mfma_f32_16x16x32_bf16(a, b, c, 0, 0, 0);
}
__device__ __forceinline__ f32x16 mfma32(bf16x8 a, bf16x8 b, f32x16 c) {
    return __builtin_amdgcn_mfma_f32_32x32x16_bf16(a, b, c, 0, 0, 0);
}

// ---------------- rope table: cos/sin[pos][d/2], 2048 x 32 ----------------
__global__ void rope_table_k(float* __restrict__ cosT, float* __restrict__ sinT) {
    int idx = blockIdx.x * 256 + threadIdx.x;   // 65536 = 2048*32
    int pos = idx >> 5, fi = idx & 31;
    double inv = pow(10000.0, -(double)(2 * fi) / 64.0);
    double ang = (double)pos * inv;
    cosT[idx] = (float)cos(ang);
    sinT[idx] = (float)sin(ang);
}

// ---------------- QKV GEMM + scale + RoPE -> Qb/Kb [B*H][N][64], Vt [B*H][64][N] ----------------
__global__ __launch_bounds__(256) void qkv_rope_k(
    const float* __restrict__ x, const float* __restrict__ w,
    const float* __restrict__ cosT, const float* __restrict__ sinT,
    bf16* __restrict__ Qb, bf16* __restrict__ Kb, bf16* __restrict__ Vt)
{
    __shared__ __align__(16) bf16 Xs[128][40];
    __shared__ __align__(16) bf16 Ws[128][40];
    const int tid = threadIdx.x, lane = tid & 63, wid = tid >> 6;
    const int wr = wid >> 1, wc = wid & 1;
    const int m0 = blockIdx.x * 128, n0 = blockIdx.y * 128;
    const int l15 = lane & 15, l4 = lane >> 4;
    const int sr = tid >> 1, sh = (tid & 1) * 16;

    f32x4 acc[4][4] = {};

    for (int kt = 0; kt < 16; ++kt) {
        __syncthreads();
        {
            const float4* xp = reinterpret_cast<const float4*>(x + (size_t)(m0 + sr) * CH_ + kt * 32 + sh);
            const float4* wp = reinterpret_cast<const float4*>(w + (size_t)(n0 + sr) * CH_ + kt * 32 + sh);
#pragma unroll
            for (int j = 0; j < 4; ++j) {
                float4 f = xp[j];
                bf16x4 o1 = { (bf16)f.x, (bf16)f.y, (bf16)f.z, (bf16)f.w };
                *reinterpret_cast<bf16x4*>(&Xs[sr][sh + j * 4]) = o1;
                float4 g = wp[j];
                bf16x4 o2 = { (bf16)g.x, (bf16)g.y, (bf16)g.z, (bf16)g.w };
                *reinterpret_cast<bf16x4*>(&Ws[sr][sh + j * 4]) = o2;
            }
        }
        __syncthreads();
        bf16x8 a[4], bb[4];
#pragma unroll
        for (int mf = 0; mf < 4; ++mf)
            a[mf] = *reinterpret_cast<const bf16x8*>(&Xs[wr * 64 + mf * 16 + l15][l4 * 8]);
#pragma unroll
        for (int nf = 0; nf < 4; ++nf)
            bb[nf] = *reinterpret_cast<const bf16x8*>(&Ws[wc * 64 + nf * 16 + l15][l4 * 8]);
#pragma unroll
        for (int mf = 0; mf < 4; ++mf)
#pragma unroll
            for (int nf = 0; nf < 4; ++nf)
                acc[mf][nf] = mfma16(a[mf], bb[nf], acc[mf][nf]);
    }

#pragma unroll
    for (int nf = 0; nf < 4; ++nf) {
        const int col = n0 + wc * 64 + nf * 16 + l15;
        const int sec = col >> 9;            // 0=Q 1=K 2=V (uniform per block)
        const int cc = col & 511;
        const int hh = cc >> 6, dd = cc & 63;
        if (sec == 2) {
            // V: store transposed Vt[bh][dd][pos], vectorized over i (4 consecutive pos)
#pragma unroll
            for (int mf = 0; mf < 4; ++mf) {
                const int pos0 = m0 + wr * 64 + mf * 16 + l4 * 4;
                const int bb_ = pos0 >> 11, pos = pos0 & 2047;
                bf16x4 pk = { (bf16)acc[mf][nf][0], (bf16)acc[mf][nf][1],
                              (bf16)acc[mf][nf][2], (bf16)acc[mf][nf][3] };
                *reinterpret_cast<bf16x4*>(
                    Vt + ((size_t)(bb_ * H_ + hh) * D_ + dd) * N_ + pos) = pk;
            }
        } else {
            const float sgn = (dd & 1) ? 1.f : -1.f;
#pragma unroll
            for (int mf = 0; mf < 4; ++mf) {
#pragma unroll
                for (int i = 0; i < 4; ++i) {
                    const int row = m0 + wr * 64 + mf * 16 + l4 * 4 + i;
                    const int bb_ = row >> 11, pos = row & 2047;
                    const float v = acc[mf][nf][i];
                    const float v2 = __shfl_xor(v, 1);   // partner d^1
                    const size_t dst = ((size_t)((bb_ * H_ + hh) * N_ + pos)) * D_ + dd;
                    const float c = cosT[pos * 32 + (dd >> 1)];
                    const float s = sinT[pos * 32 + (dd >> 1)];
                    const float r = v * c + sgn * v2 * s;
                    if (sec == 0) Qb[dst] = (bf16)(r * 0.125f);
                    else          Kb[dst] = (bf16)r;
                }
            }
        }
    }
}

// ---------------- flash attention v12: single-wave blocks, barrier-free ----------------
// 2048 blocks (XCD-swizzled) x 64 thr: each wave owns a 32-q tile and runs 64
// iters of KVBLK=32 with NO barriers -- ordering is pure counted vmcnt.
// K tile [32 k][128 B] (d), V tile [32 r][128 B] where r=d&31, col-half=d>>5;
// both use the verified ((row&7)<<4) XOR swizzle, staged via global_load_lds
// with inverse-swizzled per-lane source. Swapped QK^T (mfma32), no
// max-tracking, in-register P repack (R11-verified), bias depth-2 prefetch.
// Per-iter wait: vmcnt(4) retires GLL(t+1)+bias(t+1), leaves bias(t+2).
#define KRD32(kc)    (l31*128 + (((kc)*32 + l5*16) ^ ((l31&7)<<4)))
#define VRD32(dt,kt) (l31*128 + (((dt)*64 + (kt)*32 + l5*16) ^ ((l31&7)<<4)))

__global__ __launch_bounds__(64, 4) void attn_k(
    const bf16* __restrict__ Qb, const bf16* __restrict__ Kb, const bf16* __restrict__ Vt,
    const float* __restrict__ bias, bf16* __restrict__ AO)
{
    __shared__ __align__(16) unsigned char KsB[2][4096];
    __shared__ __align__(16) unsigned char VsB[2][4096];

    const int lane = threadIdx.x & 63;
    const int l31 = lane & 31, l5 = lane >> 5;
    // XCD swizzle: xcd owns head h=xcd across 4 batches; 64 q-tiles per bh.
    const int id = blockIdx.x;
    const int xcd = id & 7, j = id >> 3;        // j in [0,256)
    const int bh = xcd + 8 * (j >> 6);
    const int qt = j & 63;
    const int b = bh >> 3, h = bh & 7;
    const int q0 = qt * 32;
    const size_t bhoff = (size_t)bh * N_ * D_;

    // Q in regs: qreg[kc] = Q[q0+l31][kc*16 + l5*8 ..+8]  (B-operand of QK^T)
    bf16x8 qreg[4];
#pragma unroll
    for (int kc = 0; kc < 4; ++kc)
        qreg[kc] = *reinterpret_cast<const bf16x8*>(
            Qb + bhoff + (size_t)(q0 + l31) * D_ + kc * 16 + l5 * 8);

    // staging sources (inverse-swizzled). kcol = ((i&7)*16) ^ ((i>>3)<<4).
    const unsigned kcol = ((lane & 7) * 16) ^ ((lane >> 3) << 4);
    // K: lane covers row r = g*8 + (lane>>3) of the 32-row tile.
    const char* kg = (const char*)(Kb + bhoff) + (size_t)(lane >> 3) * 128 + kcol;
    // V: dest (r,c) holds d = r + 32*(ct>>6), kbyte = ct&63 (ct == kcol).
    const char* vg = (const char*)(Vt + bhoff)
        + (size_t)((lane >> 3) + 32 * (kcol >> 6)) * (N_ * 2) + (kcol & 63);

    const float* bp = bias + ((size_t)h * N_ + (q0 + l31)) * N_ + l5 * 4;

#define GLL(src, dst) __builtin_amdgcn_global_load_lds( \
        (const __attribute__((address_space(1))) unsigned int*)(src), \
        (__attribute__((address_space(3))) unsigned int*)(dst), 16, 0, 0)

// 8 GLL per tile: 4 K (rows g*8..g*8+7) + 4 V (d-groups g*8..)
#define STAGE(buf, t) do { \
        GLL(kg + (size_t)(t) * 4096,            &KsB[buf][0]); \
        GLL(kg + (size_t)(t) * 4096 + 1024,     &KsB[buf][1024]); \
        GLL(kg + (size_t)(t) * 4096 + 2048,     &KsB[buf][2048]); \
        GLL(kg + (size_t)(t) * 4096 + 3072,     &KsB[buf][3072]); \
        GLL(vg + (size_t)(t) * 64,              &VsB[buf][0]); \
        GLL(vg + (size_t)(t) * 64 + 8 * N_ * 2,  &VsB[buf][1024]); \
        GLL(vg + (size_t)(t) * 64 + 16 * N_ * 2, &VsB[buf][2048]); \
        GLL(vg + (size_t)(t) * 64 + 24 * N_ * 2, &VsB[buf][3072]); \
    } while (0)

#define WAITN(n) do { \
        asm volatile("s_waitcnt vmcnt(" #n ")" ::: "memory"); \
        __builtin_amdgcn_sched_barrier(0); \
    } while (0)

    f32x16 o[2] = {};
    float lp = 0.f;     // per-lane partial denom for q = l31 (own k-rows)
    f32x4 bc[4], bn[4], b2[4];

    // ---- prologue: stage kb=0 (GLL first), then bias(0), bias(1) ----
    STAGE(0, 0);
    __builtin_amdgcn_sched_barrier(0);
#pragma unroll
    for (int r2 = 0; r2 < 4; ++r2) {
        bc[r2] = *reinterpret_cast<const f32x4*>(bp + r2 * 8);
        bn[r2] = *reinterpret_cast<const f32x4*>(bp + 32 + r2 * 8);
    }
    WAITN(8);   // retire STAGE(0); bias(0)+bias(1) stay in flight

#pragma unroll 2
    for (int kb = 0; kb < 64; ++kb) {
        const int cur = kb & 1;
        // ---- issue next-tile GLL first (oldest vmem ops), then bias t+2 ----
        if (kb < 63) {
            STAGE(cur ^ 1, kb + 1);
            __builtin_amdgcn_sched_barrier(0);
        }
        if (kb < 62) {
#pragma unroll
            for (int r2 = 0; r2 < 4; ++r2)
                b2[r2] = *reinterpret_cast<const f32x4*>(
                    bp + (size_t)(kb + 2) * 32 + r2 * 8);
        }

        // ---- QK^T (swapped): S^T[k=32][q=32], A = K-frag, B = Q-regs ----
        const unsigned char* ksC = &KsB[cur][0];
        f32x16 s = {};
        __builtin_amdgcn_s_setprio(1);
#pragma unroll
        for (int kc = 0; kc < 4; ++kc) {
            bf16x8 kf = *reinterpret_cast<const bf16x8*>(ksC + KRD32(kc));
            s = mfma32(kf, qreg[kc], s);
        }
        __builtin_amdgcn_s_setprio(0);

        // ---- softmax (no max subtraction) + in-register P repack ----
        // lane(q=l31,h=l5) owns k-rows {8r2 + 4h + i}; safe bf16 pack.
        bf16x8 pa[2];
        {
            unsigned U[4][2], R[4][2];
#pragma unroll
            for (int r2 = 0; r2 < 4; ++r2) {
                float p0 = __expf(s[r2 * 4 + 0] + bc[r2][0]);
                float p1 = __expf(s[r2 * 4 + 1] + bc[r2][1]);
                float p2 = __expf(s[r2 * 4 + 2] + bc[r2][2]);
                float p3 = __expf(s[r2 * 4 + 3] + bc[r2][3]);
                lp += (p0 + p1) + (p2 + p3);
                bf16x4 pk = { (bf16)p0, (bf16)p1, (bf16)p2, (bf16)p3 };
                u32x2 uu = __builtin_bit_cast(u32x2, pk);
                U[r2][0] = uu[0];
                U[r2][1] = uu[1];
            }
#pragma unroll
            for (int r2 = 0; r2 < 4; ++r2) {
                R[r2][0] = __shfl_xor(U[r2][0], 32);
                R[r2][1] = __shfl_xor(U[r2][1], 32);
            }
            const bool hi = (l5 != 0);
#pragma unroll
            for (int ktp = 0; ktp < 2; ++ktp) {
                unsigned g0 = hi ? R[2 * ktp + 1][0] : U[2 * ktp][0];
                unsigned g1 = hi ? R[2 * ktp + 1][1] : U[2 * ktp][1];
                unsigned h0 = hi ? U[2 * ktp + 1][0] : R[2 * ktp][0];
                unsigned h1 = hi ? U[2 * ktp + 1][1] : R[2 * ktp][1];
                u32x4 wv = { g0, g1, h0, h1 };
                pa[ktp] = __builtin_bit_cast(bf16x8, wv);
            }
        }

        // ---- PV: O[q=32][d=64] += P@V ; B = V-frag from LDS ----
        const unsigned char* vsC = &VsB[cur][0];
        __builtin_amdgcn_s_setprio(1);
#pragma unroll
        for (int kt = 0; kt < 2; ++kt) {
#pragma unroll
            for (int dt = 0; dt < 2; ++dt) {
                bf16x8 vf = *reinterpret_cast<const bf16x8*>(vsC + VRD32(dt, kt));
                o[dt] = mfma32(pa[kt], vf, o[dt]);
            }
        }
        __builtin_amdgcn_s_setprio(0);

        // ---- rotate bias pipeline ----
#pragma unroll
        for (int r2 = 0; r2 < 4; ++r2) {
            bc[r2] = bn[r2];
            bn[r2] = b2[r2];
        }

        // ---- counted wait: GLL(kb+1)+bias(kb+1) retired, bias(kb+2) in flight ----
        if (kb < 62) { WAITN(4); } else { WAITN(0); }
    }

    // ---- epilogue: denom -> normalize -> store ----
    float tot = lp;
    tot += __shfl_xor(tot, 32);          // full softmax denom for q = l31
    float rv[16];
#pragma unroll
    for (int reg = 0; reg < 16; ++reg) {
        const int qr = (reg & 3) + 8 * (reg >> 2) + 4 * l5;
        rv[reg] = 1.0f / __shfl(tot, qr);
    }
#pragma unroll
    for (int dt = 0; dt < 2; ++dt)
#pragma unroll
        for (int reg = 0; reg < 16; ++reg) {
            const int qr = (reg & 3) + 8 * (reg >> 2) + 4 * l5;
            AO[((size_t)(b * N_ + q0 + qr)) * HID_ + h * D_ + dt * 32 + l31] =
                (bf16)(o[dt][reg] * rv[reg]);
        }
}

// ---------------- out projection: AO(bf16) @ w_out^T -> f32 ----------------
__global__ __launch_bounds__(256) void proj_k(
    const bf16* __restrict__ A, const float* __restrict__ w, float* __restrict__ out)
{
    __shared__ __align__(16) bf16 As[128][40];
    __shared__ __align__(16) bf16 Ws[128][40];
    const int tid = threadIdx.x, lane = tid & 63, wid = tid >> 6;
    const int wr = wid >> 1, wc = wid & 1;
    const int m0 = blockIdx.x * 128, n0 = blockIdx.y * 128;
    const int l15 = lane & 15, l4 = lane >> 4;
    const int sr = tid >> 1, sh = (tid & 1) * 16;

    f32x4 acc[4][4] = {};

    for (int kt = 0; kt < 16; ++kt) {
        __syncthreads();
        {
            const bf16* ap = A + (size_t)(m0 + sr) * HID_ + kt * 32 + sh;
            *reinterpret_cast<bf16x8*>(&As[sr][sh])     = *reinterpret_cast<const bf16x8*>(ap);
            *reinterpret_cast<bf16x8*>(&As[sr][sh + 8]) = *reinterpret_cast<const bf16x8*>(ap + 8);
            const float4* wp = reinterpret_cast<const float4*>(w + (size_t)(n0 + sr) * HID_ + kt * 32 + sh);
#pragma unroll
            for (int j = 0; j < 4; ++j) {
                float4 g = wp[j];
                bf16x4 o2 = { (bf16)g.x, (bf16)g.y, (bf16)g.z, (bf16)g.w };
                *reinterpret_cast<bf16x4*>(&Ws[sr][sh + j * 4]) = o2;
            }
        }
        __syncthreads();
        bf16x8 a[4], bb[4];
#pragma unroll
        for (int mf = 0; mf < 4; ++mf)
            a[mf] = *reinterpret_cast<const bf16x8*>(&As[wr * 64 + mf * 16 + l15][l4 * 8]);
#pragma unroll
        for (int nf = 0; nf < 4; ++nf)
            bb[nf] = *reinterpret_cast<const bf16x8*>(&Ws[wc * 64 + nf * 16 + l15][l4 * 8]);
#pragma unroll
        for (int mf = 0; mf < 4; ++mf)
#pragma unroll
            for (int nf = 0; nf < 4; ++nf)
                acc[mf][nf] = mfma16(a[mf], bb[nf], acc[mf][nf]);
    }
#pragma unroll
    for (int nf = 0; nf < 4; ++nf) {
        const int col = n0 + wc * 64 + nf * 16 + l15;
#pragma unroll
        for (int mf = 0; mf < 4; ++mf) {
#pragma unroll
            for (int i = 0; i < 4; ++i) {
                const int row = m0 + wr * 64 + mf * 16 + l4 * 4 + i;
                out[(size_t)row * HID_ + col] = acc[mf][nf][i];
            }
        }
    }
}

extern "C" void kernel_launch(void* const* d_in, const int* in_sizes, int n_in,
                              void* d_out, int out_size, void* d_ws, size_t ws_size,
                              hipStream_t stream) {
    (void)in_sizes; (void)n_in; (void)out_size; (void)ws_size;
    const float* x     = (const float*)d_in[0];
    const float* bias  = (const float*)d_in[1];
    const float* w_qkv = (const float*)d_in[2];
    const float* w_out = (const float*)d_in[3];
    float* out = (float*)d_out;

    bf16* Qb = (bf16*)d_ws;                 // [4*8][2048][64]
    bf16* Kb = Qb + 4194304;                // [4*8][2048][64]
    bf16* Vt = Kb + 4194304;                // [4*8][64][2048] (transposed)
    bf16* AO = Vt + 4194304;                // [4][2048][512]
    float* cosT = (float*)(AO + 4194304);   // [2048][32]
    float* sinT = cosT + 65536;

    rope_table_k<<<dim3(256), 256, 0, stream>>>(cosT, sinT);
    qkv_rope_k  <<<dim3(64, 12), 256, 0, stream>>>(x, w_qkv, cosT, sinT, Qb, Kb, Vt);
    attn_k      <<<dim3(2048), 64, 0, stream>>>(Qb, Kb, Vt, bias, AO);
    proj_k      <<<dim3(64, 4), 256, 0, stream>>>(AO, w_out, out);
}

// Round 13
// 165.015 us; speedup vs baseline: 1.0861x; 1.0861x over previous
//
#include <hip/hip_runtime.h>
#include <hip/hip_bf16.h>
#include <math.h>

typedef __bf16 bf16;
typedef bf16  bf16x8 __attribute__((ext_vector_type(8)));
typedef bf16  bf16x4 __attribute__((ext_vector_type(4)));
typedef float f32x4  __attribute__((ext_vector_type(4)));
typedef float f32x16 __attribute__((ext_vector_type(16)));

#define B_   4
#define N_   2048
#define CH_  512
#define H_   8
#define D_   64
#define HID_ 512

__device__ __forceinline__ f32x4 mfma16(bf16x8 a, bf16x8 b, f32x4 c) {
    return __builtin_amdgcn_mfma_f32_16x16x32_bf16(a, b, c, 0, 0, 0);
}
__device__ __forceinline__ f32x16 mfma32(bf16x8 a, bf16x8 b, f32x16 c) {
    return __builtin_amdgcn_mfma_f32_32x32x16_bf16(a, b, c, 0, 0, 0);
}

// ---------------- rope table: cos/sin[pos][d/2], 2048 x 32 ----------------
__global__ void rope_table_k(float* __restrict__ cosT, float* __restrict__ sinT) {
    int idx = blockIdx.x * 256 + threadIdx.x;   // 65536 = 2048*32
    int pos = idx >> 5, fi = idx & 31;
    double inv = pow(10000.0, -(double)(2 * fi) / 64.0);
    double ang = (double)pos * inv;
    cosT[idx] = (float)cos(ang);
    sinT[idx] = (float)sin(ang);
}

// ---------------- QKV GEMM + scale + RoPE -> Qb/Kb [B*H][N][64], Vt [B*H][64][N] ----------------
__global__ __launch_bounds__(256) void qkv_rope_k(
    const float* __restrict__ x, const float* __restrict__ w,
    const float* __restrict__ cosT, const float* __restrict__ sinT,
    bf16* __restrict__ Qb, bf16* __restrict__ Kb, bf16* __restrict__ Vt)
{
    __shared__ __align__(16) bf16 Xs[128][40];
    __shared__ __align__(16) bf16 Ws[128][40];
    const int tid = threadIdx.x, lane = tid & 63, wid = tid >> 6;
    const int wr = wid >> 1, wc = wid & 1;
    const int m0 = blockIdx.x * 128, n0 = blockIdx.y * 128;
    const int l15 = lane & 15, l4 = lane >> 4;
    const int sr = tid >> 1, sh = (tid & 1) * 16;

    f32x4 acc[4][4] = {};

    for (int kt = 0; kt < 16; ++kt) {
        __syncthreads();
        {
            const float4* xp = reinterpret_cast<const float4*>(x + (size_t)(m0 + sr) * CH_ + kt * 32 + sh);
            const float4* wp = reinterpret_cast<const float4*>(w + (size_t)(n0 + sr) * CH_ + kt * 32 + sh);
#pragma unroll
            for (int j = 0; j < 4; ++j) {
                float4 f = xp[j];
                bf16x4 o1 = { (bf16)f.x, (bf16)f.y, (bf16)f.z, (bf16)f.w };
                *reinterpret_cast<bf16x4*>(&Xs[sr][sh + j * 4]) = o1;
                float4 g = wp[j];
                bf16x4 o2 = { (bf16)g.x, (bf16)g.y, (bf16)g.z, (bf16)g.w };
                *reinterpret_cast<bf16x4*>(&Ws[sr][sh + j * 4]) = o2;
            }
        }
        __syncthreads();
        bf16x8 a[4], bb[4];
#pragma unroll
        for (int mf = 0; mf < 4; ++mf)
            a[mf] = *reinterpret_cast<const bf16x8*>(&Xs[wr * 64 + mf * 16 + l15][l4 * 8]);
#pragma unroll
        for (int nf = 0; nf < 4; ++nf)
            bb[nf] = *reinterpret_cast<const bf16x8*>(&Ws[wc * 64 + nf * 16 + l15][l4 * 8]);
#pragma unroll
        for (int mf = 0; mf < 4; ++mf)
#pragma unroll
            for (int nf = 0; nf < 4; ++nf)
                acc[mf][nf] = mfma16(a[mf], bb[nf], acc[mf][nf]);
    }

#pragma unroll
    for (int nf = 0; nf < 4; ++nf) {
        const int col = n0 + wc * 64 + nf * 16 + l15;
        const int sec = col >> 9;            // 0=Q 1=K 2=V (uniform per block)
        const int cc = col & 511;
        const int hh = cc >> 6, dd = cc & 63;
        if (sec == 2) {
            // V: store transposed Vt[bh][dd][pos], vectorized over i (4 consecutive pos)
#pragma unroll
            for (int mf = 0; mf < 4; ++mf) {
                const int pos0 = m0 + wr * 64 + mf * 16 + l4 * 4;
                const int bb_ = pos0 >> 11, pos = pos0 & 2047;
                bf16x4 pk = { (bf16)acc[mf][nf][0], (bf16)acc[mf][nf][1],
                              (bf16)acc[mf][nf][2], (bf16)acc[mf][nf][3] };
                *reinterpret_cast<bf16x4*>(
                    Vt + ((size_t)(bb_ * H_ + hh) * D_ + dd) * N_ + pos) = pk;
            }
        } else {
            const float sgn = (dd & 1) ? 1.f : -1.f;
#pragma unroll
            for (int mf = 0; mf < 4; ++mf) {
#pragma unroll
                for (int i = 0; i < 4; ++i) {
                    const int row = m0 + wr * 64 + mf * 16 + l4 * 4 + i;
                    const int bb_ = row >> 11, pos = row & 2047;
                    const float v = acc[mf][nf][i];
                    const float v2 = __shfl_xor(v, 1);   // partner d^1
                    const size_t dst = ((size_t)((bb_ * H_ + hh) * N_ + pos)) * D_ + dd;
                    const float c = cosT[pos * 32 + (dd >> 1)];
                    const float s = sinT[pos * 32 + (dd >> 1)];
                    const float r = v * c + sgn * v2 * s;
                    if (sec == 0) Qb[dst] = (bf16)(r * 0.125f);
                    else          Kb[dst] = (bf16)r;
                }
            }
        }
    }
}

// ---------------- flash attention v13: batch-pair bias sharing ----------------
// 512 blocks (XCD-swizzled: xcd = head), 4 waves = {batch-in-pair wb} x
// {q-subtile w}. Waves (0,w) and (1,w) read IDENTICAL bias addresses within
// one barrier period on the same CU -> bias L3 traffic halves (536->268 MB);
// adjacent bpair blocks of same qt share again in L2. Inner loop is the
// R8-verified structure verbatim: KVBLK=64, swapped QK^T (mfma32), no
// max-tracking, P through per-wave LDS, GLL dbuf staging (linear dest,
// inverse-swizzled source), counted vmcnt(8)+s_barrier, bias bc/bn regs.
// Each wave stages ONE array (w==0: K, w==1: V) of its own batch wb.
#define KRD2(kt2,kc) (((kt2)*32 + l31)*128 + (((kc)*32 + l5*16) ^ (l7<<4)))
#define VRD2(dt,kt)  (((dt)*32 + l31)*128 + (((kt)*32 + l5*16) ^ (l7<<4)))
#define PRD2(kt)     (l31*128 + (((kt)*32 + l5*16) ^ (l7<<4)))
#define PST2(kt2,r2) (l31*128 + (((kt2)*64 + (r2)*16 + l5*8) ^ (l7<<4)))

__global__ __launch_bounds__(256, 2) void attn_k(
    const bf16* __restrict__ Qb, const bf16* __restrict__ Kb, const bf16* __restrict__ Vt,
    const float* __restrict__ bias, bf16* __restrict__ AO)
{
    __shared__ __align__(16) unsigned char KsB[2][2][8192];   // [batch-in-pair][buf]
    __shared__ __align__(16) unsigned char VsB[2][2][8192];
    __shared__ __align__(16) unsigned char PwB[4][4096];      // per-wave P

    const int tid = threadIdx.x, lane = tid & 63, ww = tid >> 6;
    const int l31 = lane & 31, l5 = lane >> 5, l7 = lane & 7;
    const int wb = ww >> 1;          // batch-in-pair (0/1)
    const int w  = ww & 1;           // q-subtile + staging role (K/V)
    // decode: xcd = head; j -> (bpair, qt)
    const int id = blockIdx.x;
    const int h = id & 7, j = id >> 3;          // j in [0,64)
    const int bp = j & 1, qt = j >> 1;          // qt in [0,32)
    const int b = bp * 2 + wb;
    const int q0 = qt * 64 + w * 32;
    const size_t bhoff = (size_t)(b * H_ + h) * N_ * D_;

    // Q in regs: qreg[kc] = Q[q0+l31][kc*16 + l5*8 ..+8]  (B-operand of QK^T)
    bf16x8 qreg[4];
#pragma unroll
    for (int kc = 0; kc < 4; ++kc)
        qreg[kc] = *reinterpret_cast<const bf16x8*>(
            Qb + bhoff + (size_t)(q0 + l31) * D_ + kc * 16 + l5 * 8);

    // staging: wave (wb,w) stages {w==0: K, w==1: V} of batch wb.
    // linear LDS dest, swizzle folded into per-lane source col.
    const unsigned kcol = ((lane & 7) * 16) ^ ((lane >> 3) << 4);
    const char* sgK = (const char*)(Kb + bhoff) + (size_t)(lane >> 3) * 128 + kcol;
    const char* sgV = (const char*)(Vt + bhoff) + (size_t)(lane >> 3) * (N_ * 2) + kcol;
    const char* sg = w ? sgV : sgK;
    const size_t tstep = w ? (size_t)128 : (size_t)8192;       // per-tile src advance
    const size_t gstep = w ? (size_t)8 * N_ * 2 : (size_t)1024; // per-GLL src advance
    unsigned char* sdB = w ? &VsB[wb][0][0] : &KsB[wb][0][0];

    const float* bpp = bias + ((size_t)h * N_ + (q0 + l31)) * N_ + l5 * 4;

    unsigned char* pwD = &PwB[ww][0];

#define GLL(src, dst) __builtin_amdgcn_global_load_lds( \
        (const __attribute__((address_space(1))) unsigned int*)(src), \
        (__attribute__((address_space(3))) unsigned int*)(dst), 16, 0, 0)

// 8 GLL per wave per tile (one full 8 KB array: K or V of batch wb)
#define STAGE(buf, t) do { \
        const char* _s = sg + (size_t)(t) * tstep; \
        unsigned char* _d = sdB + (size_t)(buf) * 8192; \
        _Pragma("unroll") \
        for (int g = 0; g < 8; ++g) \
            GLL(_s + (size_t)g * gstep, _d + g * 1024); \
    } while (0)

// counted wait: retire the 8 GLL (oldest), leave the 8 newest bias loads
// in flight; then rendezvous without drain.
#define PIPE_SYNC() do { \
        asm volatile("s_waitcnt vmcnt(8)" ::: "memory"); \
        __builtin_amdgcn_sched_barrier(0); \
        __builtin_amdgcn_s_barrier(); \
        __builtin_amdgcn_sched_barrier(0); \
    } while (0)

    f32x16 o[2] = {};
    float lp = 0.f;     // per-lane partial denom for q = l31 (own k-rows)
    f32x4 bc[2][4], bn[2][4];

    // ---- prologue: stage kb=0 (GLL first!), then bias(0) ----
    STAGE(0, 0);
    __builtin_amdgcn_sched_barrier(0);
#pragma unroll
    for (int kt2 = 0; kt2 < 2; ++kt2)
#pragma unroll
        for (int r2 = 0; r2 < 4; ++r2)
            bc[kt2][r2] = *reinterpret_cast<const f32x4*>(bpp + kt2 * 32 + r2 * 8);
    PIPE_SYNC();

#pragma unroll 2
    for (int kb = 0; kb < 32; ++kb) {
        const int cur = kb & 1;
        // ---- issue next-tile GLL first (they must be the OLDEST vmem ops) ----
        if (kb < 31) {
            STAGE(cur ^ 1, kb + 1);
            __builtin_amdgcn_sched_barrier(0);   // pin: GLL before bias loads
#pragma unroll
            for (int kt2 = 0; kt2 < 2; ++kt2)
#pragma unroll
                for (int r2 = 0; r2 < 4; ++r2)
                    bn[kt2][r2] = *reinterpret_cast<const f32x4*>(
                        bpp + (size_t)(kb + 1) * 64 + kt2 * 32 + r2 * 8);
        }

        // ---- QK^T (swapped): S^T[k=64][q=32], A = K-frag, B = Q-regs ----
        const unsigned char* ksC = &KsB[wb][cur][0];
        f32x16 s[2] = {};
        __builtin_amdgcn_s_setprio(1);
#pragma unroll
        for (int kt2 = 0; kt2 < 2; ++kt2) {
#pragma unroll
            for (int kc = 0; kc < 4; ++kc) {
                bf16x8 kf = *reinterpret_cast<const bf16x8*>(ksC + KRD2(kt2, kc));
                s[kt2] = mfma32(kf, qreg[kc], s[kt2]);
            }
        }
        __builtin_amdgcn_s_setprio(0);

        // ---- softmax (no max subtraction): p = exp(s + bias), pack to LDS ----
#pragma unroll
        for (int kt2 = 0; kt2 < 2; ++kt2) {
#pragma unroll
            for (int r2 = 0; r2 < 4; ++r2) {
                float p0 = __expf(s[kt2][r2 * 4 + 0] + bc[kt2][r2][0]);
                float p1 = __expf(s[kt2][r2 * 4 + 1] + bc[kt2][r2][1]);
                float p2 = __expf(s[kt2][r2 * 4 + 2] + bc[kt2][r2][2]);
                float p3 = __expf(s[kt2][r2 * 4 + 3] + bc[kt2][r2][3]);
                lp += (p0 + p1) + (p2 + p3);
                bf16x4 pk = { (bf16)p0, (bf16)p1, (bf16)p2, (bf16)p3 };
                *reinterpret_cast<bf16x4*>(pwD + PST2(kt2, r2)) = pk;
            }
        }

        // ---- PV: O[q=32][d=64] += P@V ; A = P-frag, B = Vt-frag ----
        const unsigned char* vsC = &VsB[wb][cur][0];
        __builtin_amdgcn_s_setprio(1);
#pragma unroll
        for (int kt = 0; kt < 4; ++kt) {
            bf16x8 pa = *reinterpret_cast<const bf16x8*>(pwD + PRD2(kt));
#pragma unroll
            for (int dt = 0; dt < 2; ++dt) {
                bf16x8 vf = *reinterpret_cast<const bf16x8*>(vsC + VRD2(dt, kt));
                o[dt] = mfma32(pa, vf, o[dt]);
            }
        }
        __builtin_amdgcn_s_setprio(0);

#pragma unroll
        for (int kt2 = 0; kt2 < 2; ++kt2)
#pragma unroll
            for (int r2 = 0; r2 < 4; ++r2)
                bc[kt2][r2] = bn[kt2][r2];

        PIPE_SYNC();   // counted: GLL(t+1) retired, newest bias stays in flight
    }

    // ---- epilogue: denom -> normalize -> store ----
    float tot = lp;
    tot += __shfl_xor(tot, 32);          // full softmax denom for q = l31
    float rv[16];
#pragma unroll
    for (int reg = 0; reg < 16; ++reg) {
        const int qr = (reg & 3) + 8 * (reg >> 2) + 4 * l5;
        rv[reg] = 1.0f / __shfl(tot, qr);
    }
#pragma unroll
    for (int dt = 0; dt < 2; ++dt)
#pragma unroll
        for (int reg = 0; reg < 16; ++reg) {
            const int qr = (reg & 3) + 8 * (reg >> 2) + 4 * l5;
            AO[((size_t)(b * N_ + q0 + qr)) * HID_ + h * D_ + dt * 32 + l31] =
                (bf16)(o[dt][reg] * rv[reg]);
        }
}

// ---------------- out projection: AO(bf16) @ w_out^T -> f32 ----------------
__global__ __launch_bounds__(256) void proj_k(
    const bf16* __restrict__ A, const float* __restrict__ w, float* __restrict__ out)
{
    __shared__ __align__(16) bf16 As[128][40];
    __shared__ __align__(16) bf16 Ws[128][40];
    const int tid = threadIdx.x, lane = tid & 63, wid = tid >> 6;
    const int wr = wid >> 1, wc = wid & 1;
    const int m0 = blockIdx.x * 128, n0 = blockIdx.y * 128;
    const int l15 = lane & 15, l4 = lane >> 4;
    const int sr = tid >> 1, sh = (tid & 1) * 16;

    f32x4 acc[4][4] = {};

    for (int kt = 0; kt < 16; ++kt) {
        __syncthreads();
        {
            const bf16* ap = A + (size_t)(m0 + sr) * HID_ + kt * 32 + sh;
            *reinterpret_cast<bf16x8*>(&As[sr][sh])     = *reinterpret_cast<const bf16x8*>(ap);
            *reinterpret_cast<bf16x8*>(&As[sr][sh + 8]) = *reinterpret_cast<const bf16x8*>(ap + 8);
            const float4* wp = reinterpret_cast<const float4*>(w + (size_t)(n0 + sr) * HID_ + kt * 32 + sh);
#pragma unroll
            for (int j = 0; j < 4; ++j) {
                float4 g = wp[j];
                bf16x4 o2 = { (bf16)g.x, (bf16)g.y, (bf16)g.z, (bf16)g.w };
                *reinterpret_cast<bf16x4*>(&Ws[sr][sh + j * 4]) = o2;
            }
        }
        __syncthreads();
        bf16x8 a[4], bb[4];
#pragma unroll
        for (int mf = 0; mf < 4; ++mf)
            a[mf] = *reinterpret_cast<const bf16x8*>(&As[wr * 64 + mf * 16 + l15][l4 * 8]);
#pragma unroll
        for (int nf = 0; nf < 4; ++nf)
            bb[nf] = *reinterpret_cast<const bf16x8*>(&Ws[wc * 64 + nf * 16 + l15][l4 * 8]);
#pragma unroll
        for (int mf = 0; mf < 4; ++mf)
#pragma unroll
            for (int nf = 0; nf < 4; ++nf)
                acc[mf][nf] = mfma16(a[mf], bb[nf], acc[mf][nf]);
    }
#pragma unroll
    for (int nf = 0; nf < 4; ++nf) {
        const int col = n0 + wc * 64 + nf * 16 + l15;
#pragma unroll
        for (int mf = 0; mf < 4; ++mf) {
#pragma unroll
            for (int i = 0; i < 4; ++i) {
                const int row = m0 + wr * 64 + mf * 16 + l4 * 4 + i;
                out[(size_t)row * HID_ + col] = acc[mf][nf][i];
            }
        }
    }
}

extern "C" void kernel_launch(void* const* d_in, const int* in_sizes, int n_in,
                              void* d_out, int out_size, void* d_ws, size_t ws_size,
                              hipStream_t stream) {
    (void)in_sizes; (void)n_in; (void)out_size; (void)ws_size;
    const float* x     = (const float*)d_in[0];
    const float* bias  = (const float*)d_in[1];
    const float* w_qkv = (const float*)d_in[2];
    const float* w_out = (const float*)d_in[3];
    float* out = (float*)d_out;

    bf16* Qb = (bf16*)d_ws;                 // [4*8][2048][64]
    bf16* Kb = Qb + 4194304;                // [4*8][2048][64]
    bf16* Vt = Kb + 4194304;                // [4*8][64][2048] (transposed)
    bf16* AO = Vt + 4194304;                // [4][2048][512]
    float* cosT = (float*)(AO + 4194304);   // [2048][32]
    float* sinT = cosT + 65536;

    rope_table_k<<<dim3(256), 256, 0, stream>>>(cosT, sinT);
    qkv_rope_k  <<<dim3(64, 12), 256, 0, stream>>>(x, w_qkv, cosT, sinT, Qb, Kb, Vt);
    attn_k      <<<dim3(512), 256, 0, stream>>>(Qb, Kb, Vt, bias, AO);
    proj_k      <<<dim3(64, 4), 256, 0, stream>>>(AO, w_out, out);
}

// Round 14
// 130.722 us; speedup vs baseline: 1.3711x; 1.2623x over previous
//
#include <hip/hip_runtime.h>
#include <hip/hip_bf16.h>
#include <math.h>

typedef __bf16 bf16;
typedef bf16  bf16x8 __attribute__((ext_vector_type(8)));
typedef bf16  bf16x4 __attribute__((ext_vector_type(4)));
typedef float f32x4  __attribute__((ext_vector_type(4)));
typedef float f32x16 __attribute__((ext_vector_type(16)));

#define B_   4
#define N_   2048
#define CH_  512
#define H_   8
#define D_   64
#define HID_ 512

__device__ __forceinline__ f32x4 mfma16(bf16x8 a, bf16x8 b, f32x4 c) {
    return __builtin_amdgcn_mfma_f32_16x16x32_bf16(a, b, c, 0, 0, 0);
}
__device__ __forceinline__ f32x16 mfma32(bf16x8 a, bf16x8 b, f32x16 c) {
    return __builtin_amdgcn_mfma_f32_32x32x16_bf16(a, b, c, 0, 0, 0);
}

#define GLL(src, dst) __builtin_amdgcn_global_load_lds( \
        (const __attribute__((address_space(1))) unsigned int*)(src), \
        (__attribute__((address_space(3))) unsigned int*)(dst), 16, 0, 0)

// ---------------- prep: f32 -> bf16 for x, w_qkv, w_out ----------------
__global__ __launch_bounds__(256) void prep_k(
    const float* __restrict__ x, const float* __restrict__ wq, const float* __restrict__ wo,
    bf16* __restrict__ xb, bf16* __restrict__ wqb, bf16* __restrict__ wob)
{
    const int NX = 4194304 / 4, NQ = 786432 / 4, NO = 262144 / 4;   // quads
    const int total = NX + NQ + NO;
    for (int idx = blockIdx.x * 256 + threadIdx.x; idx < total; idx += gridDim.x * 256) {
        const float4* src; bf16* dst; int off;
        if (idx < NX)           { src = (const float4*)x;  dst = xb;  off = idx; }
        else if (idx < NX + NQ) { src = (const float4*)wq; dst = wqb; off = idx - NX; }
        else                    { src = (const float4*)wo; dst = wob; off = idx - NX - NQ; }
        float4 v = src[off];
        bf16x4 o = { (bf16)v.x, (bf16)v.y, (bf16)v.z, (bf16)v.w };
        *reinterpret_cast<bf16x4*>(dst + (size_t)off * 4) = o;
    }
}

// ---------------- rope table: cos/sin[pos][d/2], 2048 x 32 ----------------
__global__ void rope_table_k(float* __restrict__ cosT, float* __restrict__ sinT) {
    int idx = blockIdx.x * 256 + threadIdx.x;   // 65536 = 2048*32
    int pos = idx >> 5, fi = idx & 31;
    double inv = pow(10000.0, -(double)(2 * fi) / 64.0);
    double ang = (double)pos * inv;
    cosT[idx] = (float)cos(ang);
    sinT[idx] = (float)sin(ang);
}

// ---------------- QKV GEMM (bf16, GLL-staged) + scale + RoPE ----------------
// A = xb [8192][512] bf16, B = wqb [1536][512] bf16 (B^T layout). 128x128
// tile, BK=64, dbuf LDS via global_load_lds (linear dest, inverse-swizzled
// source; attn-proven pattern), 1 barrier/iter. Epilogue: RoPE scatter to
// Qb/Kb [B*H][N][64] and transposed Vt [B*H][64][N] (unchanged from R6-13).
__global__ __launch_bounds__(256) void qkv_rope_k(
    const bf16* __restrict__ xb, const bf16* __restrict__ wb,
    const float* __restrict__ cosT, const float* __restrict__ sinT,
    bf16* __restrict__ Qb, bf16* __restrict__ Kb, bf16* __restrict__ Vt)
{
    __shared__ __align__(16) unsigned char Xs[2][16384];
    __shared__ __align__(16) unsigned char Ws[2][16384];
    const int tid = threadIdx.x, lane = tid & 63, wid = tid >> 6;
    const int wr = wid >> 1, wc = wid & 1;
    const int m0 = blockIdx.x * 128, n0 = blockIdx.y * 128;
    const int l15 = lane & 15, l4 = lane >> 4;

    const unsigned scol = ((lane & 7) * 16) ^ ((lane >> 3) << 4);
    const char* ag = (const char*)xb + (size_t)(m0 + wid * 32 + (lane >> 3)) * 1024 + scol;
    const char* bg = (const char*)wb + (size_t)(n0 + wid * 32 + (lane >> 3)) * 1024 + scol;

#define QSTAGE(buf, kt) do { \
        _Pragma("unroll") \
        for (int g = 0; g < 4; ++g) { \
            GLL(ag + (size_t)(kt) * 128 + (size_t)g * 8192, &Xs[buf][wid * 4096 + g * 1024]); \
            GLL(bg + (size_t)(kt) * 128 + (size_t)g * 8192, &Ws[buf][wid * 4096 + g * 1024]); \
        } \
    } while (0)

    f32x4 acc[4][4] = {};

    QSTAGE(0, 0);
    __syncthreads();

    for (int kt = 0; kt < 8; ++kt) {
        const int cur = kt & 1;
        if (kt < 7) QSTAGE(cur ^ 1, kt + 1);
#pragma unroll
        for (int ks = 0; ks < 2; ++ks) {
            bf16x8 a[4], bb[4];
#pragma unroll
            for (int mf = 0; mf < 4; ++mf) {
                const int row = wr * 64 + mf * 16 + l15;
                a[mf] = *reinterpret_cast<const bf16x8*>(
                    &Xs[cur][row * 128 + ((ks * 64 + l4 * 16) ^ ((l15 & 7) << 4))]);
            }
#pragma unroll
            for (int nf = 0; nf < 4; ++nf) {
                const int row = wc * 64 + nf * 16 + l15;
                bb[nf] = *reinterpret_cast<const bf16x8*>(
                    &Ws[cur][row * 128 + ((ks * 64 + l4 * 16) ^ ((l15 & 7) << 4))]);
            }
#pragma unroll
            for (int mf = 0; mf < 4; ++mf)
#pragma unroll
                for (int nf = 0; nf < 4; ++nf)
                    acc[mf][nf] = mfma16(a[mf], bb[nf], acc[mf][nf]);
        }
        __syncthreads();
    }

    // epilogue (unchanged): RoPE + scatter
#pragma unroll
    for (int nf = 0; nf < 4; ++nf) {
        const int col = n0 + wc * 64 + nf * 16 + l15;
        const int sec = col >> 9;            // 0=Q 1=K 2=V (uniform per block)
        const int cc = col & 511;
        const int hh = cc >> 6, dd = cc & 63;
        if (sec == 2) {
#pragma unroll
            for (int mf = 0; mf < 4; ++mf) {
                const int pos0 = m0 + wr * 64 + mf * 16 + l4 * 4;
                const int bb_ = pos0 >> 11, pos = pos0 & 2047;
                bf16x4 pk = { (bf16)acc[mf][nf][0], (bf16)acc[mf][nf][1],
                              (bf16)acc[mf][nf][2], (bf16)acc[mf][nf][3] };
                *reinterpret_cast<bf16x4*>(
                    Vt + ((size_t)(bb_ * H_ + hh) * D_ + dd) * N_ + pos) = pk;
            }
        } else {
            const float sgn = (dd & 1) ? 1.f : -1.f;
#pragma unroll
            for (int mf = 0; mf < 4; ++mf) {
#pragma unroll
                for (int i = 0; i < 4; ++i) {
                    const int row = m0 + wr * 64 + mf * 16 + l4 * 4 + i;
                    const int bb_ = row >> 11, pos = row & 2047;
                    const float v = acc[mf][nf][i];
                    const float v2 = __shfl_xor(v, 1);   // partner d^1
                    const size_t dst = ((size_t)((bb_ * H_ + hh) * N_ + pos)) * D_ + dd;
                    const float c = cosT[pos * 32 + (dd >> 1)];
                    const float s = sinT[pos * 32 + (dd >> 1)];
                    const float r = v * c + sgn * v2 * s;
                    if (sec == 0) Qb[dst] = (bf16)(r * 0.125f);
                    else          Kb[dst] = (bf16)r;
                }
            }
        }
    }
}

// ---------------- flash attention (R6-verbatim, best measured: ~105 us) ----------------
// 1024 blocks (XCD-swizzled), 2 waves x 32 q-rows, KVBLK=64, swapped QK^T
// (mfma32), no max-tracking, bias reg-dbuf, GLL dbuf staging, Vt.
#define KRD2(kt2,kc) (((kt2)*32 + l31)*128 + (((kc)*32 + l5*16) ^ (l7<<4)))
#define VRD2(dt,kt)  (((dt)*32 + l31)*128 + (((kt)*32 + l5*16) ^ (l7<<4)))
#define PRD2(kt)     (wid*4096 + l31*128 + (((kt)*32 + l5*16) ^ (l7<<4)))
#define PST2(kt2,r2) (wid*4096 + l31*128 + (((kt2)*64 + (r2)*16 + l5*8) ^ (l7<<4)))

__global__ __launch_bounds__(128, 2) void attn_k(
    const bf16* __restrict__ Qb, const bf16* __restrict__ Kb, const bf16* __restrict__ Vt,
    const float* __restrict__ bias, bf16* __restrict__ AO)
{
    __shared__ __align__(16) unsigned char KsB[2][8192];
    __shared__ __align__(16) unsigned char VsB[2][8192];
    __shared__ __align__(16) unsigned char PwB[2][4096];

    const int tid = threadIdx.x, lane = tid & 63, wid = tid >> 6;
    const int l31 = lane & 31, l5 = lane >> 5, l7 = lane & 7;
    const int id = blockIdx.x;
    const int xcd = id & 7, j = id >> 3;
    const int bh = xcd + 8 * (j >> 5);
    const int qt = j & 31;
    const int b = bh >> 3, h = bh & 7;
    const int q0 = qt * 64 + wid * 32;
    const size_t bhoff = (size_t)bh * N_ * D_;

    bf16x8 qreg[4];
#pragma unroll
    for (int kc = 0; kc < 4; ++kc)
        qreg[kc] = *reinterpret_cast<const bf16x8*>(
            Qb + bhoff + (size_t)(q0 + l31) * D_ + kc * 16 + l5 * 8);

    const unsigned scol = ((lane & 7) * 16) ^ ((lane >> 3) << 4);
    const char* kg = (const char*)(Kb + bhoff) + (size_t)(wid * 32 + (lane >> 3)) * 128 + scol;
    const char* vg = (const char*)(Vt + bhoff) + (size_t)(wid * 32 + (lane >> 3)) * (N_ * 2) + scol;

    const float* bp = bias + ((size_t)h * N_ + (q0 + l31)) * N_ + l5 * 4;

    unsigned char* pwD = &PwB[0][0];

#define STAGE(buf, t) do { \
        GLL(kg + (size_t)(t) * 8192,            &KsB[buf][wid * 4096]); \
        GLL(kg + (size_t)(t) * 8192 + 1024,     &KsB[buf][wid * 4096 + 1024]); \
        GLL(kg + (size_t)(t) * 8192 + 2048,     &KsB[buf][wid * 4096 + 2048]); \
        GLL(kg + (size_t)(t) * 8192 + 3072,     &KsB[buf][wid * 4096 + 3072]); \
        GLL(vg + (size_t)(t) * 128,             &VsB[buf][wid * 4096]); \
        GLL(vg + (size_t)(t) * 128 + 32768,     &VsB[buf][wid * 4096 + 1024]); \
        GLL(vg + (size_t)(t) * 128 + 65536,     &VsB[buf][wid * 4096 + 2048]); \
        GLL(vg + (size_t)(t) * 128 + 98304,     &VsB[buf][wid * 4096 + 3072]); \
    } while (0)

    f32x16 o[2] = {};
    float lp = 0.f;
    f32x4 bc[2][4], bn[2][4];

    STAGE(0, 0);
#pragma unroll
    for (int kt2 = 0; kt2 < 2; ++kt2)
#pragma unroll
        for (int r2 = 0; r2 < 4; ++r2)
            bc[kt2][r2] = *reinterpret_cast<const f32x4*>(bp + kt2 * 32 + r2 * 8);
    __syncthreads();

#pragma unroll 2
    for (int kb = 0; kb < 32; ++kb) {
        const int cur = kb & 1;
        if (kb < 31) {
            STAGE(cur ^ 1, kb + 1);
#pragma unroll
            for (int kt2 = 0; kt2 < 2; ++kt2)
#pragma unroll
                for (int r2 = 0; r2 < 4; ++r2)
                    bn[kt2][r2] = *reinterpret_cast<const f32x4*>(
                        bp + (size_t)(kb + 1) * 64 + kt2 * 32 + r2 * 8);
        }

        const unsigned char* ksC = &KsB[cur][0];
        f32x16 s[2] = {};
        __builtin_amdgcn_s_setprio(1);
#pragma unroll
        for (int kt2 = 0; kt2 < 2; ++kt2) {
#pragma unroll
            for (int kc = 0; kc < 4; ++kc) {
                bf16x8 kf = *reinterpret_cast<const bf16x8*>(ksC + KRD2(kt2, kc));
                s[kt2] = mfma32(kf, qreg[kc], s[kt2]);
            }
        }
        __builtin_amdgcn_s_setprio(0);

#pragma unroll
        for (int kt2 = 0; kt2 < 2; ++kt2) {
#pragma unroll
            for (int r2 = 0; r2 < 4; ++r2) {
                float p0 = __expf(s[kt2][r2 * 4 + 0] + bc[kt2][r2][0]);
                float p1 = __expf(s[kt2][r2 * 4 + 1] + bc[kt2][r2][1]);
                float p2 = __expf(s[kt2][r2 * 4 + 2] + bc[kt2][r2][2]);
                float p3 = __expf(s[kt2][r2 * 4 + 3] + bc[kt2][r2][3]);
                lp += (p0 + p1) + (p2 + p3);
                bf16x4 pk = { (bf16)p0, (bf16)p1, (bf16)p2, (bf16)p3 };
                *reinterpret_cast<bf16x4*>(pwD + PST2(kt2, r2)) = pk;
            }
        }

        const unsigned char* vsC = &VsB[cur][0];
        __builtin_amdgcn_s_setprio(1);
#pragma unroll
        for (int kt = 0; kt < 4; ++kt) {
            bf16x8 pa = *reinterpret_cast<const bf16x8*>(pwD + PRD2(kt));
#pragma unroll
            for (int dt = 0; dt < 2; ++dt) {
                bf16x8 vf = *reinterpret_cast<const bf16x8*>(vsC + VRD2(dt, kt));
                o[dt] = mfma32(pa, vf, o[dt]);
            }
        }
        __builtin_amdgcn_s_setprio(0);

#pragma unroll
        for (int kt2 = 0; kt2 < 2; ++kt2)
#pragma unroll
            for (int r2 = 0; r2 < 4; ++r2)
                bc[kt2][r2] = bn[kt2][r2];
        __syncthreads();
    }

    float tot = lp;
    tot += __shfl_xor(tot, 32);
    float rv[16];
#pragma unroll
    for (int reg = 0; reg < 16; ++reg) {
        const int qr = (reg & 3) + 8 * (reg >> 2) + 4 * l5;
        rv[reg] = 1.0f / __shfl(tot, qr);
    }
#pragma unroll
    for (int dt = 0; dt < 2; ++dt)
#pragma unroll
        for (int reg = 0; reg < 16; ++reg) {
            const int qr = (reg & 3) + 8 * (reg >> 2) + 4 * l5;
            AO[((size_t)(b * N_ + q0 + qr)) * HID_ + h * D_ + dt * 32 + l31] =
                (bf16)(o[dt][reg] * rv[reg]);
        }
}

// ---------------- out projection (bf16, GLL-staged): AO @ wob^T -> f32 ----------------
__global__ __launch_bounds__(256) void proj_k(
    const bf16* __restrict__ A, const bf16* __restrict__ wob, float* __restrict__ out)
{
    __shared__ __align__(16) unsigned char Xs[2][16384];
    __shared__ __align__(16) unsigned char Ws[2][16384];
    const int tid = threadIdx.x, lane = tid & 63, wid = tid >> 6;
    const int wr = wid >> 1, wc = wid & 1;
    const int m0 = blockIdx.x * 128, n0 = blockIdx.y * 128;
    const int l15 = lane & 15, l4 = lane >> 4;

    const unsigned scol = ((lane & 7) * 16) ^ ((lane >> 3) << 4);
    const char* ag = (const char*)A   + (size_t)(m0 + wid * 32 + (lane >> 3)) * 1024 + scol;
    const char* bg = (const char*)wob + (size_t)(n0 + wid * 32 + (lane >> 3)) * 1024 + scol;

#define PSTAGE(buf, kt) do { \
        _Pragma("unroll") \
        for (int g = 0; g < 4; ++g) { \
            GLL(ag + (size_t)(kt) * 128 + (size_t)g * 8192, &Xs[buf][wid * 4096 + g * 1024]); \
            GLL(bg + (size_t)(kt) * 128 + (size_t)g * 8192, &Ws[buf][wid * 4096 + g * 1024]); \
        } \
    } while (0)

    f32x4 acc[4][4] = {};

    PSTAGE(0, 0);
    __syncthreads();

    for (int kt = 0; kt < 8; ++kt) {
        const int cur = kt & 1;
        if (kt < 7) PSTAGE(cur ^ 1, kt + 1);
#pragma unroll
        for (int ks = 0; ks < 2; ++ks) {
            bf16x8 a[4], bb[4];
#pragma unroll
            for (int mf = 0; mf < 4; ++mf) {
                const int row = wr * 64 + mf * 16 + l15;
                a[mf] = *reinterpret_cast<const bf16x8*>(
                    &Xs[cur][row * 128 + ((ks * 64 + l4 * 16) ^ ((l15 & 7) << 4))]);
            }
#pragma unroll
            for (int nf = 0; nf < 4; ++nf) {
                const int row = wc * 64 + nf * 16 + l15;
                bb[nf] = *reinterpret_cast<const bf16x8*>(
                    &Ws[cur][row * 128 + ((ks * 64 + l4 * 16) ^ ((l15 & 7) << 4))]);
            }
#pragma unroll
            for (int mf = 0; mf < 4; ++mf)
#pragma unroll
                for (int nf = 0; nf < 4; ++nf)
                    acc[mf][nf] = mfma16(a[mf], bb[nf], acc[mf][nf]);
        }
        __syncthreads();
    }

#pragma unroll
    for (int nf = 0; nf < 4; ++nf) {
        const int col = n0 + wc * 64 + nf * 16 + l15;
#pragma unroll
        for (int mf = 0; mf < 4; ++mf) {
#pragma unroll
            for (int i = 0; i < 4; ++i) {
                const int row = m0 + wr * 64 + mf * 16 + l4 * 4 + i;
                out[(size_t)row * HID_ + col] = acc[mf][nf][i];
            }
        }
    }
}

extern "C" void kernel_launch(void* const* d_in, const int* in_sizes, int n_in,
                              void* d_out, int out_size, void* d_ws, size_t ws_size,
                              hipStream_t stream) {
    (void)in_sizes; (void)n_in; (void)out_size; (void)ws_size;
    const float* x     = (const float*)d_in[0];
    const float* bias  = (const float*)d_in[1];
    const float* w_qkv = (const float*)d_in[2];
    const float* w_out = (const float*)d_in[3];
    float* out = (float*)d_out;

    bf16* base = (bf16*)d_ws;
    bf16* Qb = base;                         // [4*8][2048][64]
    bf16* Kb = base + 4194304;               // [4*8][2048][64]
    bf16* Vt = base + 8388608;               // [4*8][64][2048] (transposed)
    bf16* AO = base + 12582912;              // [4][2048][512]; ALSO xb before attn
    bf16* xb = AO;                           // aliases AO (xb dead before attn writes)
    float* cosT = (float*)(base + 16777216); // [2048][32]
    float* sinT = cosT + 65536;
    bf16* wqb = (bf16*)(sinT + 65536);       // [1536][512]
    bf16* wob = wqb + 786432;                // [512][512]

    prep_k      <<<dim3(2560), 256, 0, stream>>>(x, w_qkv, w_out, xb, wqb, wob);
    rope_table_k<<<dim3(256), 256, 0, stream>>>(cosT, sinT);
    qkv_rope_k  <<<dim3(64, 12), 256, 0, stream>>>(xb, wqb, cosT, sinT, Qb, Kb, Vt);
    attn_k      <<<dim3(1024), 128, 0, stream>>>(Qb, Kb, Vt, bias, AO);
    proj_k      <<<dim3(64, 4), 256, 0, stream>>>(AO, wob, out);
}